// Round 4
// baseline (685.827 us; speedup 1.0000x reference)
//
#include <hip/hip_runtime.h>

// SparseResBlock on MI355X — round 3: spatially-sorted voxels (deterministic
// compaction of the dense table), full-cout no-LDS conv with 32x32x16 MFMA,
// packed global weight fragments, XCD-chunked tile mapping, fused stats.

constexpr int N_VOX = 200000;
constexpr int GEXT  = 128;
constexpr int C     = 64;
constexpr int K27   = 27;
constexpr int TBL_N = 2 * GEXT * GEXT * GEXT;  // 4,194,304
constexpr float EPSF = 1e-5f;
constexpr int NCBLK = 1563;   // conv grid: ceil(200000 / 128)

using short8   = __attribute__((ext_vector_type(8))) short;
using floatx16 = __attribute__((ext_vector_type(16))) float;

static __device__ __forceinline__ ushort f2bf(float f) {
  union { float f; unsigned u; } a; a.f = f;
  unsigned r = a.u + 0x7fff + ((a.u >> 16) & 1);  // RTNE
  return (ushort)(r >> 16);
}
static __device__ __forceinline__ float bf2f(ushort h) {
  union { unsigned u; float f; } a; a.u = ((unsigned)h) << 16;
  return a.f;
}

__global__ __launch_bounds__(256) void k_fill(int* __restrict__ t,
                                              int* __restrict__ bsum,
                                              ushort* __restrict__ zrow) {
  int i = blockIdx.x * 256 + threadIdx.x;
  if (i < TBL_N) t[i] = -1;
  if (i < 4096) bsum[i] = 0;
  if (i < 64) zrow[i] = 0;
}

__global__ __launch_bounds__(256) void k_scatter(const int* __restrict__ coords,
                                                 int* __restrict__ t) {
  int n = blockIdx.x * 256 + threadIdx.x;
  if (n >= N_VOX) return;
  int4 c = reinterpret_cast<const int4*>(coords)[n];
  int lin = ((c.x * GEXT + c.y) * GEXT + c.z) * GEXT + c.w;
  t[lin] = n;
}

// integer atomics -> deterministic counts per 1024-cell chunk
__global__ __launch_bounds__(256) void k_count(const int* __restrict__ coords,
                                               int* __restrict__ bsum) {
  int n = blockIdx.x * 256 + threadIdx.x;
  if (n >= N_VOX) return;
  int4 c = reinterpret_cast<const int4*>(coords)[n];
  int lin = ((c.x * GEXT + c.y) * GEXT + c.z) * GEXT + c.w;
  atomicAdd(&bsum[lin >> 10], 1);
}

// exclusive scan of 4096 chunk counts (1 block, deterministic)
__global__ __launch_bounds__(1024) void k_scan(const int* __restrict__ bsum,
                                               int* __restrict__ boff) {
  __shared__ int sc[1024];
  int t = threadIdx.x;
  int v0 = bsum[t * 4], v1 = bsum[t * 4 + 1], v2 = bsum[t * 4 + 2],
      v3 = bsum[t * 4 + 3];
  int s = v0 + v1 + v2 + v3;
  sc[t] = s;
  __syncthreads();
  for (int off = 1; off < 1024; off <<= 1) {
    int x = (t >= off) ? sc[t - off] : 0;
    __syncthreads();
    sc[t] += x;
    __syncthreads();
  }
  int excl = sc[t] - s;
  boff[t * 4]     = excl;
  boff[t * 4 + 1] = excl + v0;
  boff[t * 4 + 2] = excl + v0 + v1;
  boff[t * 4 + 3] = excl + v0 + v1 + v2;
}

// compact: perm[rank] = orig voxel id; table cell rewritten to rank
__global__ __launch_bounds__(1024) void k_compact(int* __restrict__ table,
                                                  const int* __restrict__ boff,
                                                  int* __restrict__ perm) {
  __shared__ int wsum[16];
  int i = blockIdx.x * 1024 + threadIdx.x;
  int orig = table[i];
  bool valid = orig >= 0;
  unsigned long long bal = __ballot(valid);
  int lane = threadIdx.x & 63, wv = threadIdx.x >> 6;
  int before = __popcll(bal & ((1ull << lane) - 1ull));
  if (lane == 0) wsum[wv] = __popcll(bal);
  __syncthreads();
  int woff = 0;
  for (int w = 0; w < 16; ++w) woff += (w < wv) ? wsum[w] : 0;
  if (valid) {
    int j = boff[blockIdx.x] + woff + before;
    perm[j] = orig;
    table[i] = j;
  }
}

// neighbor ranks in permuted space: nbrp[k][j] = rank of neighbor of perm[j]
__global__ __launch_bounds__(256) void k_nbrp(const int* __restrict__ coords,
                                              const int* __restrict__ table,
                                              const int* __restrict__ perm,
                                              int* __restrict__ nbrp) {
  int j = blockIdx.x * 256 + threadIdx.x;
  if (j >= N_VOX) return;
  int orig = perm[j];
  int4 c = reinterpret_cast<const int4*>(coords)[orig];
  int k = 0;
  #pragma unroll
  for (int dx = -1; dx <= 1; ++dx)
    #pragma unroll
    for (int dy = -1; dy <= 1; ++dy)
      #pragma unroll
      for (int dz = -1; dz <= 1; ++dz) {
        int x = c.y + dx, y = c.z + dy, z = c.w + dz;
        int rank = -1;
        if (((unsigned)x < (unsigned)GEXT) & ((unsigned)y < (unsigned)GEXT) &
            ((unsigned)z < (unsigned)GEXT)) {
          int lin = ((c.x * GEXT + x) * GEXT + y) * GEXT + z;
          rank = table[lin];
        }
        nbrp[k * N_VOX + j] = rank;
        ++k;
      }
}

// fbp[j][c] = bf16(feats[perm[j]][c])   (gather rows into permuted order)
__global__ __launch_bounds__(256) void k_gcast(const float* __restrict__ feats,
                                               const int* __restrict__ perm,
                                               ushort* __restrict__ fbp) {
  int i = blockIdx.x * 256 + threadIdx.x;  // N*16 quads
  int j = i >> 4, seg = i & 15;
  int p = perm[j];
  float4 v = reinterpret_cast<const float4*>(feats)[(p << 4) + seg];
  ushort4 o;
  o.x = f2bf(v.x); o.y = f2bf(v.y); o.z = f2bf(v.z); o.w = f2bf(v.w);
  reinterpret_cast<ushort4*>(fbp)[i] = o;
}

// w[k][ci][co] f32 -> packed A-frags for mfma_32x32x16:
// [k][ch(2)][ks(4)][hi1(2)][row32][e8] bf16; lane l reads 16B at +l*16.
__global__ __launch_bounds__(256) void k_castw(const float* __restrict__ w,
                                               ushort* __restrict__ wp) {
  int i = blockIdx.x * 256 + threadIdx.x;
  if (i >= K27 * 4096) return;
  int k = i >> 12, r = i & 4095, ci = r >> 6, co = r & 63;
  int ch = co >> 5, row = co & 31;
  int ks = ci >> 4, hi1 = (ci >> 3) & 1, e = ci & 7;
  int dst = ((((k * 2 + ch) * 4 + ks) * 2 + hi1) << 8) + row * 8 + e;
  wp[dst] = f2bf(w[i]);
}

// Conv: block = 512 thr = 8 waves = 4 vox-subtiles x 2 cout-halves.
// Wave: 32 vox x 32 cout, K=64 via 4x mfma_32x32x16. No LDS staging, no
// barriers in main loop; weights from L1/L2; ballot k-skip; fused stats.
template <bool OUT_BF16>
__global__ __launch_bounds__(512, 4) void k_conv32(
    const ushort* __restrict__ fin,   // [N][64] bf16, permuted space
    const ushort* __restrict__ wp,    // packed weight frags
    const int* __restrict__ nbrp,     // [27][N] ranks
    const int* __restrict__ perm,     // rank -> orig (for scatter out)
    const ushort* __restrict__ zrow,  // 64 zeros
    void* __restrict__ fout,
    float* __restrict__ part) {       // [NCBLK][128]
  __shared__ float sred[8][2][32];
  const int tid = threadIdx.x, lane = tid & 63, wv = tid >> 6;
  const int lo = lane & 31, hi = lane >> 5;
  const int ch = wv & 1, vh = wv >> 1;
  // XCD-chunked bijective tile mapping (NCBLK = 8*195 + 3)
  const int xcd = blockIdx.x & 7, bi = blockIdx.x >> 3;
  const int tb = xcd * 195 + (xcd < 3 ? xcd : 3) + bi;
  const int n0 = tb * 128 + vh * 32;

  float s16[16], ss16[16];
  #pragma unroll
  for (int j = 0; j < 16; ++j) { s16[j] = 0.f; ss16[j] = 0.f; }

  if (n0 < N_VOX) {
    floatx16 acc;
    #pragma unroll
    for (int j = 0; j < 16; ++j) acc[j] = 0.f;

    const char* wbase = (const char*)wp + (ch << 12) + (lane << 4);
    #pragma unroll
    for (int k = 0; k < K27; ++k) {
      int idx = nbrp[k * N_VOX + n0 + lo];
      if (__ballot(idx >= 0)) {
        const char* base = (idx >= 0)
            ? (const char*)fin + ((size_t)idx << 7)
            : (const char*)zrow;
        const char* wk = wbase + (k << 13);
        #pragma unroll
        for (int ks = 0; ks < 4; ++ks) {
          short8 bf = *(const short8*)(base + (ks << 5) + (hi << 4));
          short8 af = *(const short8*)(wk + (ks << 10));
          acc = __builtin_amdgcn_mfma_f32_32x32x16_bf16(af, bf, acc, 0, 0, 0);
        }
      }
    }

    // D layout: vox = lo, cout = ch*32 + rg*8 + hi*4 + r3 (reg = rg*4+r3)
    if (OUT_BF16) {
      ushort* o = (ushort*)fout + ((size_t)(n0 + lo) << 6) + (ch << 5) + (hi << 2);
      #pragma unroll
      for (int rg = 0; rg < 4; ++rg) {
        ushort4 v;
        v.x = f2bf(acc[rg * 4 + 0]); v.y = f2bf(acc[rg * 4 + 1]);
        v.z = f2bf(acc[rg * 4 + 2]); v.w = f2bf(acc[rg * 4 + 3]);
        *(ushort4*)(o + (rg << 3)) = v;
      }
    } else {
      int p = perm[n0 + lo];
      float* o = (float*)fout + ((size_t)p << 6) + (ch << 5) + (hi << 2);
      #pragma unroll
      for (int rg = 0; rg < 4; ++rg) {
        float4 v = {acc[rg * 4 + 0], acc[rg * 4 + 1],
                    acc[rg * 4 + 2], acc[rg * 4 + 3]};
        *(float4*)(o + (rg << 3)) = v;
      }
    }
    #pragma unroll
    for (int j = 0; j < 16; ++j) {
      float v = acc[j];
      s16[j] += v; ss16[j] += v * v;
    }
  }

  // reduce stats over the 32 vox-lanes (lo); hi (bit 5) preserved
  #pragma unroll
  for (int j = 0; j < 16; ++j) {
    float s = s16[j], ss = ss16[j];
    #pragma unroll
    for (int m = 1; m < 32; m <<= 1) {
      s += __shfl_xor(s, m); ss += __shfl_xor(ss, m);
    }
    if (lo == 0) { sred[wv][hi][j] = s; sred[wv][hi][16 + j] = ss; }
  }
  __syncthreads();
  if (tid < 128) {
    int halfsel = tid >> 6, c = tid & 63;
    int chh = c >> 5, w32 = c & 31;
    int rg = w32 >> 3, hi1 = (w32 >> 2) & 1, r3 = c & 3;
    int j = halfsel * 16 + rg * 4 + r3;
    float v = 0.f;
    #pragma unroll
    for (int vhh = 0; vhh < 4; ++vhh) v += sred[vhh * 2 + chh][hi1][j];
    part[(size_t)blockIdx.x * 128 + tid] = v;
  }
}

// reduce NCBLK partials -> ab[c]=scale, ab[64+c]=shift
__global__ __launch_bounds__(256) void k_bnfin(const float* __restrict__ part,
                                               const float* __restrict__ gamma,
                                               const float* __restrict__ beta,
                                               float* __restrict__ ab) {
  __shared__ float red[256];
  __shared__ float fin[128];
  int tid = threadIdx.x;
  int e = tid & 127, g = tid >> 7;
  float s = 0.f;
  for (int b = g; b < NCBLK; b += 2) s += part[(size_t)b * 128 + e];
  red[tid] = s;
  __syncthreads();
  if (tid < 128) fin[tid] = red[tid] + red[tid + 128];
  __syncthreads();
  if (tid < 64) {
    float su = fin[tid], ss = fin[64 + tid];
    float mean = su / (float)N_VOX;
    float var  = ss / (float)N_VOX - mean * mean;
    float a = gamma[tid] * rsqrtf(var + EPSF);
    ab[tid]      = a;
    ab[64 + tid] = beta[tid] - mean * a;
  }
}

// BN + ReLU in place on bf16, 8 elems/thread
__global__ __launch_bounds__(256) void k_bnrelu8(ushort* __restrict__ x,
                                                 const float* __restrict__ ab) {
  int i = blockIdx.x * 256 + threadIdx.x;  // N*8 groups
  ushort4 v0 = reinterpret_cast<ushort4*>(x)[i * 2];
  ushort4 v1 = reinterpret_cast<ushort4*>(x)[i * 2 + 1];
  int cb = (i * 8) & 63;
  v0.x = f2bf(fmaxf(bf2f(v0.x) * ab[cb]     + ab[64 + cb],     0.f));
  v0.y = f2bf(fmaxf(bf2f(v0.y) * ab[cb + 1] + ab[64 + cb + 1], 0.f));
  v0.z = f2bf(fmaxf(bf2f(v0.z) * ab[cb + 2] + ab[64 + cb + 2], 0.f));
  v0.w = f2bf(fmaxf(bf2f(v0.w) * ab[cb + 3] + ab[64 + cb + 3], 0.f));
  v1.x = f2bf(fmaxf(bf2f(v1.x) * ab[cb + 4] + ab[64 + cb + 4], 0.f));
  v1.y = f2bf(fmaxf(bf2f(v1.y) * ab[cb + 5] + ab[64 + cb + 5], 0.f));
  v1.z = f2bf(fmaxf(bf2f(v1.z) * ab[cb + 6] + ab[64 + cb + 6], 0.f));
  v1.w = f2bf(fmaxf(bf2f(v1.w) * ab[cb + 7] + ab[64 + cb + 7], 0.f));
  reinterpret_cast<ushort4*>(x)[i * 2]     = v0;
  reinterpret_cast<ushort4*>(x)[i * 2 + 1] = v1;
}

// BN2 + residual(f32 feats) + ReLU, in place on f32 d_out (original order)
__global__ __launch_bounds__(256) void k_final4(float* __restrict__ h2,
                                                const float* __restrict__ feats,
                                                const float* __restrict__ ab) {
  int i = blockIdx.x * 256 + threadIdx.x;
  float4 a = reinterpret_cast<float4*>(h2)[i];
  float4 f = reinterpret_cast<const float4*>(feats)[i];
  int cb = (i * 4) & 63;
  float4 o;
  o.x = fmaxf(a.x * ab[cb]     + ab[64 + cb]     + f.x, 0.f);
  o.y = fmaxf(a.y * ab[cb + 1] + ab[64 + cb + 1] + f.y, 0.f);
  o.z = fmaxf(a.z * ab[cb + 2] + ab[64 + cb + 2] + f.z, 0.f);
  o.w = fmaxf(a.w * ab[cb + 3] + ab[64 + cb + 3] + f.w, 0.f);
  reinterpret_cast<float4*>(h2)[i] = o;
}

extern "C" void kernel_launch(void* const* d_in, const int* in_sizes, int n_in,
                              void* d_out, int out_size, void* d_ws, size_t ws_size,
                              hipStream_t stream) {
  const float* feats  = (const float*)d_in[0];
  const float* w1     = (const float*)d_in[1];
  const float* g1     = (const float*)d_in[2];
  const float* b1     = (const float*)d_in[3];
  const float* w2     = (const float*)d_in[4];
  const float* g2     = (const float*)d_in[5];
  const float* b2     = (const float*)d_in[6];
  const int*   coords = (const int*)d_in[7];
  float* out = (float*)d_out;

  char* ws = (char*)d_ws;
  int*    table = (int*)ws;     ws += (size_t)TBL_N * 4;
  int*    nbrp  = (int*)ws;     ws += (size_t)K27 * N_VOX * 4;
  ushort* fbp   = (ushort*)ws;  ws += (size_t)N_VOX * C * 2;
  ushort* h1p   = (ushort*)ws;  ws += (size_t)N_VOX * C * 2;
  int*    perm  = (int*)ws;     ws += (size_t)N_VOX * 4;
  ushort* wp1   = (ushort*)ws;  ws += (size_t)K27 * 4096 * 2;
  ushort* wp2   = (ushort*)ws;  ws += (size_t)K27 * 4096 * 2;
  int*    bsum  = (int*)ws;     ws += 4096 * 4;
  int*    boff  = (int*)ws;     ws += 4096 * 4;
  float*  ab1   = (float*)ws;   ws += 512;
  float*  ab2   = (float*)ws;   ws += 512;
  ushort* zrow  = (ushort*)ws;  ws += 128;
  float*  part  = (float*)table;  // alias: table dead after k_nbrp

  k_fill<<<TBL_N / 256, 256, 0, stream>>>(table, bsum, zrow);
  k_scatter<<<(N_VOX + 255) / 256, 256, 0, stream>>>(coords, table);
  k_count<<<(N_VOX + 255) / 256, 256, 0, stream>>>(coords, bsum);
  k_scan<<<1, 1024, 0, stream>>>(bsum, boff);
  k_compact<<<TBL_N / 1024, 1024, 0, stream>>>(table, boff, perm);
  k_nbrp<<<(N_VOX + 255) / 256, 256, 0, stream>>>(coords, table, perm, nbrp);
  k_gcast<<<N_VOX * 16 / 256, 256, 0, stream>>>(feats, perm, fbp);
  k_castw<<<(K27 * 4096 + 255) / 256, 256, 0, stream>>>(w1, wp1);
  k_castw<<<(K27 * 4096 + 255) / 256, 256, 0, stream>>>(w2, wp2);

  k_conv32<true><<<NCBLK, 512, 0, stream>>>(fbp, wp1, nbrp, perm, zrow, h1p, part);
  k_bnfin<<<1, 256, 0, stream>>>(part, g1, b1, ab1);
  k_bnrelu8<<<N_VOX * 8 / 256, 256, 0, stream>>>(h1p, ab1);

  k_conv32<false><<<NCBLK, 512, 0, stream>>>(h1p, wp2, nbrp, perm, zrow, out, part);
  k_bnfin<<<1, 256, 0, stream>>>(part, g2, b2, ab2);
  k_final4<<<N_VOX * 64 / 4 / 256, 256, 0, stream>>>(out, feats, ab2);
}

// Round 5
// 323.340 us; speedup vs baseline: 2.1211x; 2.1211x over previous
//
#include <hip/hip_runtime.h>

// SparseResBlock on MI355X — round 4: sorted voxels + exec-masked direct
// gather conv (64-vox wave tiles, 32x32x16 MFMA, weights from L1/L2),
// two-stage deterministic BN reduction, fused stats in conv epilogue.

constexpr int N_VOX = 200000;
constexpr int GEXT  = 128;
constexpr int C     = 64;
constexpr int K27   = 27;
constexpr int TBL_N = 2 * GEXT * GEXT * GEXT;  // 4,194,304
constexpr float EPSF = 1e-5f;
constexpr int NCBLK = 1563;   // ceil(200000 / 128)
constexpr int RBLK  = 128;    // stage-1 reduce blocks

using short8   = __attribute__((ext_vector_type(8))) short;
using floatx16 = __attribute__((ext_vector_type(16))) float;

static __device__ __forceinline__ ushort f2bf(float f) {
  union { float f; unsigned u; } a; a.f = f;
  unsigned r = a.u + 0x7fff + ((a.u >> 16) & 1);  // RTNE
  return (ushort)(r >> 16);
}
static __device__ __forceinline__ float bf2f(ushort h) {
  union { unsigned u; float f; } a; a.u = ((unsigned)h) << 16;
  return a.f;
}

__global__ __launch_bounds__(256) void k_fill(int* __restrict__ t,
                                              int* __restrict__ bsum) {
  int i = blockIdx.x * 256 + threadIdx.x;
  if (i < TBL_N) t[i] = -1;
  if (i < 4096) bsum[i] = 0;
}

__global__ __launch_bounds__(256) void k_scatter(const int* __restrict__ coords,
                                                 int* __restrict__ t) {
  int n = blockIdx.x * 256 + threadIdx.x;
  if (n >= N_VOX) return;
  int4 c = reinterpret_cast<const int4*>(coords)[n];
  int lin = ((c.x * GEXT + c.y) * GEXT + c.z) * GEXT + c.w;
  t[lin] = n;
}

__global__ __launch_bounds__(256) void k_count(const int* __restrict__ coords,
                                               int* __restrict__ bsum) {
  int n = blockIdx.x * 256 + threadIdx.x;
  if (n >= N_VOX) return;
  int4 c = reinterpret_cast<const int4*>(coords)[n];
  int lin = ((c.x * GEXT + c.y) * GEXT + c.z) * GEXT + c.w;
  atomicAdd(&bsum[lin >> 10], 1);
}

__global__ __launch_bounds__(1024) void k_scan(const int* __restrict__ bsum,
                                               int* __restrict__ boff) {
  __shared__ int sc[1024];
  int t = threadIdx.x;
  int v0 = bsum[t * 4], v1 = bsum[t * 4 + 1], v2 = bsum[t * 4 + 2],
      v3 = bsum[t * 4 + 3];
  int s = v0 + v1 + v2 + v3;
  sc[t] = s;
  __syncthreads();
  for (int off = 1; off < 1024; off <<= 1) {
    int x = (t >= off) ? sc[t - off] : 0;
    __syncthreads();
    sc[t] += x;
    __syncthreads();
  }
  int excl = sc[t] - s;
  boff[t * 4]     = excl;
  boff[t * 4 + 1] = excl + v0;
  boff[t * 4 + 2] = excl + v0 + v1;
  boff[t * 4 + 3] = excl + v0 + v1 + v2;
}

__global__ __launch_bounds__(1024) void k_compact(int* __restrict__ table,
                                                  const int* __restrict__ boff,
                                                  int* __restrict__ perm) {
  __shared__ int wsum[16];
  int i = blockIdx.x * 1024 + threadIdx.x;
  int orig = table[i];
  bool valid = orig >= 0;
  unsigned long long bal = __ballot(valid);
  int lane = threadIdx.x & 63, wv = threadIdx.x >> 6;
  int before = __popcll(bal & ((1ull << lane) - 1ull));
  if (lane == 0) wsum[wv] = __popcll(bal);
  __syncthreads();
  int woff = 0;
  for (int w = 0; w < 16; ++w) woff += (w < wv) ? wsum[w] : 0;
  if (valid) {
    int j = boff[blockIdx.x] + woff + before;
    perm[j] = orig;
    table[i] = j;
  }
}

__global__ __launch_bounds__(256) void k_nbrp(const int* __restrict__ coords,
                                              const int* __restrict__ table,
                                              const int* __restrict__ perm,
                                              int* __restrict__ nbrp) {
  int j = blockIdx.x * 256 + threadIdx.x;
  if (j >= N_VOX) return;
  int orig = perm[j];
  int4 c = reinterpret_cast<const int4*>(coords)[orig];
  int k = 0;
  #pragma unroll
  for (int dx = -1; dx <= 1; ++dx)
    #pragma unroll
    for (int dy = -1; dy <= 1; ++dy)
      #pragma unroll
      for (int dz = -1; dz <= 1; ++dz) {
        int x = c.y + dx, y = c.z + dy, z = c.w + dz;
        int rank = -1;
        if (((unsigned)x < (unsigned)GEXT) & ((unsigned)y < (unsigned)GEXT) &
            ((unsigned)z < (unsigned)GEXT)) {
          int lin = ((c.x * GEXT + x) * GEXT + y) * GEXT + z;
          rank = table[lin];
        }
        nbrp[k * N_VOX + j] = rank;
        ++k;
      }
}

__global__ __launch_bounds__(256) void k_gcast(const float* __restrict__ feats,
                                               const int* __restrict__ perm,
                                               ushort* __restrict__ fbp) {
  int i = blockIdx.x * 256 + threadIdx.x;  // N*16 quads
  int j = i >> 4, seg = i & 15;
  int p = perm[j];
  float4 v = reinterpret_cast<const float4*>(feats)[(p << 4) + seg];
  ushort4 o;
  o.x = f2bf(v.x); o.y = f2bf(v.y); o.z = f2bf(v.z); o.w = f2bf(v.w);
  reinterpret_cast<ushort4*>(fbp)[i] = o;
}

// w[k][ci][co] f32 -> packed A-frags for mfma_32x32x16:
// [k][ch(2)][ks(4)][hi1(2)][row32][e8] bf16; lane l reads 16B at +l*16.
__global__ __launch_bounds__(256) void k_castw(const float* __restrict__ w,
                                               ushort* __restrict__ wp) {
  int i = blockIdx.x * 256 + threadIdx.x;
  if (i >= K27 * 4096) return;
  int k = i >> 12, r = i & 4095, ci = r >> 6, co = r & 63;
  int ch = co >> 5, row = co & 31;
  int ks = ci >> 4, hi1 = (ci >> 3) & 1, e = ci & 7;
  int dst = ((((k * 2 + ch) * 4 + ks) * 2 + hi1) << 8) + row * 8 + e;
  wp[dst] = f2bf(w[i]);
}

// Conv: block = 256 thr = 4 waves = 2 vox-groups x 2 cout-halves.
// Wave: 64 vox (two 32-vox B-subtiles sharing A-frags) x 32 cout, K=64.
// Exec-masked gathers (invalid lanes fetch nothing), no LDS, no barriers
// in main loop, idx prefetch, ballot k-skip, fused stats.
template <bool OUT_BF16>
__global__ __launch_bounds__(256, 4) void k_convd(
    const ushort* __restrict__ fin,   // [N][64] bf16, permuted space
    const ushort* __restrict__ wp,    // packed weight frags
    const int* __restrict__ nbrp,     // [27][N] ranks
    const int* __restrict__ perm,     // rank -> orig
    void* __restrict__ fout,
    float* __restrict__ part) {       // [NCBLK][128]
  __shared__ float sred[4][2][32];
  const int tid = threadIdx.x, lane = tid & 63, wv = tid >> 6;
  const int lo = lane & 31, hi = lane >> 5;
  const int ch = wv & 1, vh = wv >> 1;
  // XCD-chunked bijective tile mapping (NCBLK = 8*195 + 3)
  const int xcd = blockIdx.x & 7, bi = blockIdx.x >> 3;
  const int tb = xcd * 195 + (xcd < 3 ? xcd : 3) + bi;
  const int n0 = tb * 128 + vh * 64;
  const int vA = n0 + lo, vB = n0 + 32 + lo;
  const bool okA = vA < N_VOX, okB = vB < N_VOX;

  floatx16 accA, accB;
  #pragma unroll
  for (int j = 0; j < 16; ++j) { accA[j] = 0.f; accB[j] = 0.f; }

  const char* wk = (const char*)wp + (ch << 12) + (lane << 4);
  int idxA = okA ? nbrp[vA] : -1;
  int idxB = okB ? nbrp[vB] : -1;

  #pragma unroll 1
  for (int k = 0; k < K27; ++k) {
    int nxA = -1, nxB = -1;
    if (k + 1 < K27) {
      nxA = okA ? nbrp[(k + 1) * N_VOX + vA] : -1;
      nxB = okB ? nbrp[(k + 1) * N_VOX + vB] : -1;
    }
    bool anyA = __ballot(idxA >= 0) != 0ull;
    bool anyB = __ballot(idxB >= 0) != 0ull;
    if (anyA || anyB) {
      short8 a0 = *(const short8*)(wk);
      short8 a1 = *(const short8*)(wk + 1024);
      short8 a2 = *(const short8*)(wk + 2048);
      short8 a3 = *(const short8*)(wk + 3072);
      if (anyA) {
        short8 b0, b1, b2, b3;
        if (idxA >= 0) {
          const char* b = (const char*)fin + ((size_t)idxA << 7) + (hi << 4);
          b0 = *(const short8*)(b);
          b1 = *(const short8*)(b + 32);
          b2 = *(const short8*)(b + 64);
          b3 = *(const short8*)(b + 96);
        } else {
          b0 = short8{0,0,0,0,0,0,0,0}; b1 = b0; b2 = b0; b3 = b0;
        }
        accA = __builtin_amdgcn_mfma_f32_32x32x16_bf16(a0, b0, accA, 0, 0, 0);
        accA = __builtin_amdgcn_mfma_f32_32x32x16_bf16(a1, b1, accA, 0, 0, 0);
        accA = __builtin_amdgcn_mfma_f32_32x32x16_bf16(a2, b2, accA, 0, 0, 0);
        accA = __builtin_amdgcn_mfma_f32_32x32x16_bf16(a3, b3, accA, 0, 0, 0);
      }
      if (anyB) {
        short8 b0, b1, b2, b3;
        if (idxB >= 0) {
          const char* b = (const char*)fin + ((size_t)idxB << 7) + (hi << 4);
          b0 = *(const short8*)(b);
          b1 = *(const short8*)(b + 32);
          b2 = *(const short8*)(b + 64);
          b3 = *(const short8*)(b + 96);
        } else {
          b0 = short8{0,0,0,0,0,0,0,0}; b1 = b0; b2 = b0; b3 = b0;
        }
        accB = __builtin_amdgcn_mfma_f32_32x32x16_bf16(a0, b0, accB, 0, 0, 0);
        accB = __builtin_amdgcn_mfma_f32_32x32x16_bf16(a1, b1, accB, 0, 0, 0);
        accB = __builtin_amdgcn_mfma_f32_32x32x16_bf16(a2, b2, accB, 0, 0, 0);
        accB = __builtin_amdgcn_mfma_f32_32x32x16_bf16(a3, b3, accB, 0, 0, 0);
      }
    }
    wk += 8192;
    idxA = nxA; idxB = nxB;
  }

  // D layout: vox = lo, cout = ch*32 + rg*8 + hi*4 + r3
  if (okA || okB) {
    #pragma unroll
    for (int sub = 0; sub < 2; ++sub) {
      const floatx16& acc = sub ? accB : accA;
      int vox = sub ? vB : vA;
      bool ok = sub ? okB : okA;
      if (!ok) continue;
      if (OUT_BF16) {
        ushort* o = (ushort*)fout + ((size_t)vox << 6) + (ch << 5) + (hi << 2);
        #pragma unroll
        for (int rg = 0; rg < 4; ++rg) {
          ushort4 v;
          v.x = f2bf(acc[rg * 4 + 0]); v.y = f2bf(acc[rg * 4 + 1]);
          v.z = f2bf(acc[rg * 4 + 2]); v.w = f2bf(acc[rg * 4 + 3]);
          *(ushort4*)(o + (rg << 3)) = v;
        }
      } else {
        int p = perm[vox];
        float* o = (float*)fout + ((size_t)p << 6) + (ch << 5) + (hi << 2);
        #pragma unroll
        for (int rg = 0; rg < 4; ++rg) {
          float4 v = {acc[rg * 4 + 0], acc[rg * 4 + 1],
                      acc[rg * 4 + 2], acc[rg * 4 + 3]};
          *(float4*)(o + (rg << 3)) = v;
        }
      }
    }
  }

  // fused stats: sum over this wave's 64 voxels per cout-reg j
  #pragma unroll
  for (int j = 0; j < 16; ++j) {
    float s  = accA[j] + accB[j];
    float ss = accA[j] * accA[j] + accB[j] * accB[j];
    #pragma unroll
    for (int m = 1; m < 32; m <<= 1) {
      s += __shfl_xor(s, m); ss += __shfl_xor(ss, m);
    }
    if (lo == 0) { sred[wv][hi][j] = s; sred[wv][hi][16 + j] = ss; }
  }
  __syncthreads();
  if (tid < 128) {
    int halfsel = tid >> 6, c = tid & 63;
    int chh = c >> 5, w32 = c & 31;
    int rg = w32 >> 3, hi1 = (w32 >> 2) & 1, r3 = c & 3;
    int j = halfsel * 16 + rg * 4 + r3;
    float v = sred[chh][hi1][j] + sred[2 + chh][hi1][j];
    part[(size_t)blockIdx.x * 128 + tid] = v;
  }
}

// stage-1 reduce: NCBLK rows -> RBLK rows
__global__ __launch_bounds__(256) void k_red(const float* __restrict__ part,
                                             float* __restrict__ part2) {
  __shared__ float red[256];
  int tid = threadIdx.x;
  int e = tid & 127, g = tid >> 7;
  float s = 0.f;
  for (int r = blockIdx.x * 2 + g; r < NCBLK; r += 2 * RBLK)
    s += part[(size_t)r * 128 + e];
  red[tid] = s;
  __syncthreads();
  if (tid < 128) part2[(size_t)blockIdx.x * 128 + tid] = red[tid] + red[tid + 128];
}

// stage-2: RBLK rows -> ab[c]=scale, ab[64+c]=shift
__global__ __launch_bounds__(256) void k_bnfin(const float* __restrict__ part2,
                                               const float* __restrict__ gamma,
                                               const float* __restrict__ beta,
                                               float* __restrict__ ab) {
  __shared__ float fin[128];
  int tid = threadIdx.x;
  if (tid < 128) {
    float s = 0.f;
    for (int r = 0; r < RBLK; ++r) s += part2[(size_t)r * 128 + tid];
    fin[tid] = s;
  }
  __syncthreads();
  if (tid < 64) {
    float su = fin[tid], ss = fin[64 + tid];
    float mean = su / (float)N_VOX;
    float var  = ss / (float)N_VOX - mean * mean;
    float a = gamma[tid] * rsqrtf(var + EPSF);
    ab[tid]      = a;
    ab[64 + tid] = beta[tid] - mean * a;
  }
}

__global__ __launch_bounds__(256) void k_bnrelu8(ushort* __restrict__ x,
                                                 const float* __restrict__ ab) {
  int i = blockIdx.x * 256 + threadIdx.x;  // N*8 groups
  ushort4 v0 = reinterpret_cast<ushort4*>(x)[i * 2];
  ushort4 v1 = reinterpret_cast<ushort4*>(x)[i * 2 + 1];
  int cb = (i * 8) & 63;
  v0.x = f2bf(fmaxf(bf2f(v0.x) * ab[cb]     + ab[64 + cb],     0.f));
  v0.y = f2bf(fmaxf(bf2f(v0.y) * ab[cb + 1] + ab[64 + cb + 1], 0.f));
  v0.z = f2bf(fmaxf(bf2f(v0.z) * ab[cb + 2] + ab[64 + cb + 2], 0.f));
  v0.w = f2bf(fmaxf(bf2f(v0.w) * ab[cb + 3] + ab[64 + cb + 3], 0.f));
  v1.x = f2bf(fmaxf(bf2f(v1.x) * ab[cb + 4] + ab[64 + cb + 4], 0.f));
  v1.y = f2bf(fmaxf(bf2f(v1.y) * ab[cb + 5] + ab[64 + cb + 5], 0.f));
  v1.z = f2bf(fmaxf(bf2f(v1.z) * ab[cb + 6] + ab[64 + cb + 6], 0.f));
  v1.w = f2bf(fmaxf(bf2f(v1.w) * ab[cb + 7] + ab[64 + cb + 7], 0.f));
  reinterpret_cast<ushort4*>(x)[i * 2]     = v0;
  reinterpret_cast<ushort4*>(x)[i * 2 + 1] = v1;
}

__global__ __launch_bounds__(256) void k_final4(float* __restrict__ h2,
                                                const float* __restrict__ feats,
                                                const float* __restrict__ ab) {
  int i = blockIdx.x * 256 + threadIdx.x;
  float4 a = reinterpret_cast<float4*>(h2)[i];
  float4 f = reinterpret_cast<const float4*>(feats)[i];
  int cb = (i * 4) & 63;
  float4 o;
  o.x = fmaxf(a.x * ab[cb]     + ab[64 + cb]     + f.x, 0.f);
  o.y = fmaxf(a.y * ab[cb + 1] + ab[64 + cb + 1] + f.y, 0.f);
  o.z = fmaxf(a.z * ab[cb + 2] + ab[64 + cb + 2] + f.z, 0.f);
  o.w = fmaxf(a.w * ab[cb + 3] + ab[64 + cb + 3] + f.w, 0.f);
  reinterpret_cast<float4*>(h2)[i] = o;
}

extern "C" void kernel_launch(void* const* d_in, const int* in_sizes, int n_in,
                              void* d_out, int out_size, void* d_ws, size_t ws_size,
                              hipStream_t stream) {
  const float* feats  = (const float*)d_in[0];
  const float* w1     = (const float*)d_in[1];
  const float* g1     = (const float*)d_in[2];
  const float* b1     = (const float*)d_in[3];
  const float* w2     = (const float*)d_in[4];
  const float* g2     = (const float*)d_in[5];
  const float* b2     = (const float*)d_in[6];
  const int*   coords = (const int*)d_in[7];
  float* out = (float*)d_out;

  char* ws = (char*)d_ws;
  int*    table = (int*)ws;     ws += (size_t)TBL_N * 4;
  int*    nbrp  = (int*)ws;     ws += (size_t)K27 * N_VOX * 4;
  ushort* fbp   = (ushort*)ws;  ws += (size_t)N_VOX * C * 2;
  ushort* h1p   = (ushort*)ws;  ws += (size_t)N_VOX * C * 2;
  int*    perm  = (int*)ws;     ws += (size_t)N_VOX * 4;
  ushort* wp1   = (ushort*)ws;  ws += (size_t)K27 * 4096 * 2;
  ushort* wp2   = (ushort*)ws;  ws += (size_t)K27 * 4096 * 2;
  int*    bsum  = (int*)ws;     ws += 4096 * 4;
  int*    boff  = (int*)ws;     ws += 4096 * 4;
  float*  part2 = (float*)ws;   ws += (size_t)RBLK * 128 * 4;
  float*  ab1   = (float*)ws;   ws += 512;
  float*  ab2   = (float*)ws;   ws += 512;
  float*  part  = (float*)table;  // alias: table dead after k_nbrp

  k_fill<<<TBL_N / 256, 256, 0, stream>>>(table, bsum);
  k_scatter<<<(N_VOX + 255) / 256, 256, 0, stream>>>(coords, table);
  k_count<<<(N_VOX + 255) / 256, 256, 0, stream>>>(coords, bsum);
  k_scan<<<1, 1024, 0, stream>>>(bsum, boff);
  k_compact<<<TBL_N / 1024, 1024, 0, stream>>>(table, boff, perm);
  k_nbrp<<<(N_VOX + 255) / 256, 256, 0, stream>>>(coords, table, perm, nbrp);
  k_gcast<<<N_VOX * 16 / 256, 256, 0, stream>>>(feats, perm, fbp);
  k_castw<<<(K27 * 4096 + 255) / 256, 256, 0, stream>>>(w1, wp1);
  k_castw<<<(K27 * 4096 + 255) / 256, 256, 0, stream>>>(w2, wp2);

  k_convd<true><<<NCBLK, 256, 0, stream>>>(fbp, wp1, nbrp, perm, h1p, part);
  k_red<<<RBLK, 256, 0, stream>>>(part, part2);
  k_bnfin<<<1, 256, 0, stream>>>(part2, g1, b1, ab1);
  k_bnrelu8<<<N_VOX * 8 / 256, 256, 0, stream>>>(h1p, ab1);

  k_convd<false><<<NCBLK, 256, 0, stream>>>(h1p, wp2, nbrp, perm, out, part);
  k_red<<<RBLK, 256, 0, stream>>>(part, part2);
  k_bnfin<<<1, 256, 0, stream>>>(part2, g2, b2, ab2);
  k_final4<<<N_VOX * 64 / 4 / 256, 256, 0, stream>>>(out, feats, ab2);
}